// Round 2
// baseline (831.665 us; speedup 1.0000x reference)
//
#include <hip/hip_runtime.h>

// VQ: B=200000 rows (D=128 fp32) vs K=1024 codes; out = [quant B*D | codes B] fp32.
//
// R4: R3 was LDS-read-throughput-bound (6 ds_read_b128/wave/d = 288 CU-cycles
// of the shared per-CU LDS pipe vs 128 VALU cycles/SIMD -> VALUBusy capped at
// ~62%). Fix: move x to the SCALAR path. Waves own row-groups (16 rows,
// wave-uniform) -> x fetched via s_load_dwordx2 into SGPRs, consumed as
// v_pk_fma_f32 src0 (SGPR operand + op_sel broadcast). Only the codebook
// tile stays in LDS: ONE conflict-free ds_read_b128 per lane per d.
// cs double-buffered, one barrier per 16-dim chunk; per-lane argmin state +
// 64-lane shfl butterfly. xs tile deleted.
// Numerics: identical fma chains (dot: serial over d per tile; xsq: 4-chain),
// identical dist formula and tie-breaks -> bit-identical to R2/R3 outputs.

typedef float v2f __attribute__((ext_vector_type(2)));
typedef int   v2i __attribute__((ext_vector_type(2)));

#define DDIM 128
#define KCODES 1024
#define BM 64              // rows per block (200000 = 3125 * 64, exact)
#define BN 256             // codes per tile
#define DCH 16             // d-chunk staged in LDS
#define NTILES (KCODES / BN)   // 4
#define NCHUNK (DDIM / DCH)    // 8

__global__ void csq_kernel(const float* __restrict__ cb, float* __restrict__ csq) {
    int k = blockIdx.x * blockDim.x + threadIdx.x;
    if (k >= KCODES) return;
    const float* __restrict__ c = cb + (long)k * DDIM;
    float s0 = 0.f, s1 = 0.f, s2 = 0.f, s3 = 0.f;
#pragma unroll
    for (int d = 0; d < DDIM; d += 4) {
        s0 = fmaf(c[d + 0], c[d + 0], s0);
        s1 = fmaf(c[d + 1], c[d + 1], s1);
        s2 = fmaf(c[d + 2], c[d + 2], s2);
        s3 = fmaf(c[d + 3], c[d + 3], s3);
    }
    csq[k] = (s0 + s1) + (s2 + s3);
}

// v_pk_fma_f32 with SGPR pair src0 (x dims d,d+1) broadcast via op_sel.
// PKL: both halves use src0.lo (dim d). PKH: both use src0.hi (dim d+1).
// src1 = c pair (two codes at that dim), src2 = acc (standard lo/hi).
#define PKL(a, xx, cc) \
    asm("v_pk_fma_f32 %0, %1, %2, %0 op_sel:[0,0,0] op_sel_hi:[0,1,1]" \
        : "+v"(a) : "s"(xx), "v"(cc))
#define PKH(a, xx, cc) \
    asm("v_pk_fma_f32 %0, %1, %2, %0 op_sel:[1,0,0] op_sel_hi:[1,1,1]" \
        : "+v"(a) : "s"(xx), "v"(cc))

#define FOR16(M) M(0) M(1) M(2) M(3) M(4) M(5) M(6) M(7) \
                 M(8) M(9) M(10) M(11) M(12) M(13) M(14) M(15)

__launch_bounds__(256, 3)  // VGPR cap ~170; LDS 33KB; -> 3 blocks/CU
__global__ void vq_gemm_kernel(const float* __restrict__ x, const float* __restrict__ cb,
                               const float* __restrict__ csq, float* __restrict__ quant,
                               float* __restrict__ codes) {
    __shared__ float cs[2][DCH * BN];   // double-buffered codebook chunk, [d][k]
    __shared__ int win[BM];

    const int tid = threadIdx.x;
    const long r0 = (long)blockIdx.x * BM;
    const int lane = tid & 63;
    const int wv = __builtin_amdgcn_readfirstlane(tid >> 6);  // wave id, SGPR
    const int wr0 = wv * 16;                                  // wave's row base

    // ---- xsq: lanes 0..15 compute row wr0+lane from global (exact 4-chain) ----
    float xsq_mine = 0.f;
    if (lane < 16) {
        const float* __restrict__ xr = x + (r0 + wr0 + lane) * DDIM;
        float s0 = 0.f, s1 = 0.f, s2 = 0.f, s3 = 0.f;
#pragma unroll
        for (int q = 0; q < 32; ++q) {
            const float4 v = *(const float4*)(xr + q * 4);
            s0 = fmaf(v.x, v.x, s0);
            s1 = fmaf(v.y, v.y, s1);
            s2 = fmaf(v.z, v.z, s2);
            s3 = fmaf(v.w, v.w, s3);
        }
        xsq_mine = (s0 + s1) + (s2 + s3);
    }
    float xsqall[16];
#pragma unroll
    for (int r = 0; r < 16; ++r) xsqall[r] = __shfl(xsq_mine, r);

    // ---- prologue: stage chunk 0 (tile 0, dims 0..15) into cs[0] ----
    {
        const float* __restrict__ crow = cb + (long)tid * DDIM;
#pragma unroll
        for (int j = 0; j < 4; ++j) {
            const float4 v = *(const float4*)(crow + j * 4);
            cs[0][(j * 4 + 0) * BN + tid] = v.x;
            cs[0][(j * 4 + 1) * BN + tid] = v.y;
            cs[0][(j * 4 + 2) * BN + tid] = v.z;
            cs[0][(j * 4 + 3) * BN + tid] = v.w;
        }
    }
    __syncthreads();

    float best[16];
    int bidx[16];
#pragma unroll
    for (int r = 0; r < 16; ++r) { best[r] = 3.4e38f; bidx[r] = 0; }

    v2f acc[16][2];   // [row][code-pair]: codes lane*4+{0,1} and lane*4+{2,3}

#pragma unroll 1
    for (int t = 0; t < NTILES * NCHUNK; ++t) {   // 32 chunks
        const int ct = t >> 3;
        const int dc = t & 7;
        if (dc == 0) {
#define ZA(R) acc[R][0] = (v2f){0.f, 0.f}; acc[R][1] = (v2f){0.f, 0.f};
            FOR16(ZA)
#undef ZA
        }

        // issue prefetch of chunk t+1 into regs (latency hides under compute)
        float4 pf0, pf1, pf2, pf3;
        if (t < NTILES * NCHUNK - 1) {
            const int nt = t + 1;
            const float* __restrict__ crow =
                cb + (long)(((nt >> 3) * BN) + tid) * DDIM + (nt & 7) * DCH;
            pf0 = *(const float4*)(crow + 0);
            pf1 = *(const float4*)(crow + 4);
            pf2 = *(const float4*)(crow + 8);
            pf3 = *(const float4*)(crow + 12);
        }

        const float* csp = cs[t & 1];
#pragma unroll 1
        for (int sub = 0; sub < 8; ++sub) {   // 2 dims per sub
            const float* xb = x + (r0 + wr0) * DDIM + dc * DCH + sub * 2;
            v2i xq0, xq1, xq2, xq3, xq4, xq5, xq6, xq7,
                xq8, xq9, xq10, xq11, xq12, xq13, xq14, xq15;
            asm volatile(
                "s_load_dwordx2 %[a0],  %[xb], 0x0\n\t"
                "s_load_dwordx2 %[a1],  %[xb], 0x200\n\t"
                "s_load_dwordx2 %[a2],  %[xb], 0x400\n\t"
                "s_load_dwordx2 %[a3],  %[xb], 0x600\n\t"
                "s_load_dwordx2 %[a4],  %[xb], 0x800\n\t"
                "s_load_dwordx2 %[a5],  %[xb], 0xa00\n\t"
                "s_load_dwordx2 %[a6],  %[xb], 0xc00\n\t"
                "s_load_dwordx2 %[a7],  %[xb], 0xe00\n\t"
                "s_load_dwordx2 %[a8],  %[xb], 0x1000\n\t"
                "s_load_dwordx2 %[a9],  %[xb], 0x1200\n\t"
                "s_load_dwordx2 %[a10], %[xb], 0x1400\n\t"
                "s_load_dwordx2 %[a11], %[xb], 0x1600\n\t"
                "s_load_dwordx2 %[a12], %[xb], 0x1800\n\t"
                "s_load_dwordx2 %[a13], %[xb], 0x1a00\n\t"
                "s_load_dwordx2 %[a14], %[xb], 0x1c00\n\t"
                "s_load_dwordx2 %[a15], %[xb], 0x1e00\n\t"
                "s_waitcnt lgkmcnt(0)"
                : [a0] "=s"(xq0), [a1] "=s"(xq1), [a2] "=s"(xq2), [a3] "=s"(xq3),
                  [a4] "=s"(xq4), [a5] "=s"(xq5), [a6] "=s"(xq6), [a7] "=s"(xq7),
                  [a8] "=s"(xq8), [a9] "=s"(xq9), [a10] "=s"(xq10), [a11] "=s"(xq11),
                  [a12] "=s"(xq12), [a13] "=s"(xq13), [a14] "=s"(xq14), [a15] "=s"(xq15)
                : [xb] "s"(xb));

            const int dl = sub * 2;
            const float4 ca  = *(const float4*)&csp[dl * BN + lane * 4];
            const float4 cb4 = *(const float4*)&csp[(dl + 1) * BN + lane * 4];
            v2f cp0 = (v2f){ca.x, ca.y},  cp1 = (v2f){ca.z, ca.w};
            v2f cp2 = (v2f){cb4.x, cb4.y}, cp3 = (v2f){cb4.z, cb4.w};

            // dim d for all rows (32 indep pk), then dim d+1 (chain dist = 32)
#define SL(R) PKL(acc[R][0], xq##R, cp0); PKL(acc[R][1], xq##R, cp1);
            FOR16(SL)
#undef SL
#define SH(R) PKH(acc[R][0], xq##R, cp2); PKH(acc[R][1], xq##R, cp3);
            FOR16(SH)
#undef SH
        }

        // finish staging chunk t+1 into the other buffer
        if (t < NTILES * NCHUNK - 1) {
            float* dst = cs[(t + 1) & 1];
            dst[(0) * BN + tid]  = pf0.x;
            dst[(1) * BN + tid]  = pf0.y;
            dst[(2) * BN + tid]  = pf0.z;
            dst[(3) * BN + tid]  = pf0.w;
            dst[(4) * BN + tid]  = pf1.x;
            dst[(5) * BN + tid]  = pf1.y;
            dst[(6) * BN + tid]  = pf1.z;
            dst[(7) * BN + tid]  = pf1.w;
            dst[(8) * BN + tid]  = pf2.x;
            dst[(9) * BN + tid]  = pf2.y;
            dst[(10) * BN + tid] = pf2.z;
            dst[(11) * BN + tid] = pf2.w;
            dst[(12) * BN + tid] = pf3.x;
            dst[(13) * BN + tid] = pf3.y;
            dst[(14) * BN + tid] = pf3.z;
            dst[(15) * BN + tid] = pf3.w;
        }

        // ---- tile epilogue (after last chunk of tile): dist + running argmin ----
        if (dc == 7) {
            const int cb0 = ct * BN + lane * 4;
            const float4 cq = *(const float4*)&csq[cb0];
#define EPI(R) { \
            const float t0 = fmaf(-2.0f, acc[R][0][0], xsqall[R]) + cq.x; \
            if (t0 < best[R]) { best[R] = t0; bidx[R] = cb0 + 0; } \
            const float t1 = fmaf(-2.0f, acc[R][0][1], xsqall[R]) + cq.y; \
            if (t1 < best[R]) { best[R] = t1; bidx[R] = cb0 + 1; } \
            const float t2 = fmaf(-2.0f, acc[R][1][0], xsqall[R]) + cq.z; \
            if (t2 < best[R]) { best[R] = t2; bidx[R] = cb0 + 2; } \
            const float t3 = fmaf(-2.0f, acc[R][1][1], xsqall[R]) + cq.w; \
            if (t3 < best[R]) { best[R] = t3; bidx[R] = cb0 + 3; } }
            FOR16(EPI)
#undef EPI
        }
        __syncthreads();
    }

    // ---- per-row argmin across the wave's 64 lanes (value, then index) ----
#define RED(R) \
    _Pragma("unroll") \
    for (int off = 32; off >= 1; off >>= 1) { \
        const float ov = __shfl_xor(best[R], off); \
        const int oi = __shfl_xor(bidx[R], off); \
        if (ov < best[R] || (ov == best[R] && oi < bidx[R])) { \
            best[R] = ov; bidx[R] = oi; } }
    FOR16(RED)
#undef RED

    if (lane == 0) {
#define WRW(R) codes[r0 + wr0 + R] = (float)bidx[R]; win[wr0 + R] = bidx[R];
        FOR16(WRW)
#undef WRW
    }
    __syncthreads();

    // ---- gather winner rows ----
    {
        const int r = tid >> 2;
        const int qb = (tid & 3) * 8;
        const float* __restrict__ crow = cb + (long)win[r] * DDIM;
        float* __restrict__ qrow = quant + (r0 + r) * DDIM;
#pragma unroll
        for (int j = 0; j < 8; ++j) {
            const int q = qb + j;
            *(float4*)(qrow + q * 4) = *(const float4*)(crow + q * 4);
        }
    }
}

extern "C" void kernel_launch(void* const* d_in, const int* in_sizes, int n_in,
                              void* d_out, int out_size, void* d_ws, size_t ws_size,
                              hipStream_t stream) {
    const float* x  = (const float*)d_in[0];
    const float* cb = (const float*)d_in[1];
    const int B = in_sizes[0] / DDIM;  // 200000

    float* quant = (float*)d_out;
    float* codes = (float*)d_out + (size_t)B * DDIM;
    float* csq   = (float*)d_ws;

    csq_kernel<<<(KCODES + 255) / 256, 256, 0, stream>>>(cb, csq);

    const int blocks = B / BM;  // 3125 exact
    vq_gemm_kernel<<<blocks, 256, 0, stream>>>(x, cb, csq, quant, codes);
}

// Round 3
// 709.677 us; speedup vs baseline: 1.1719x; 1.1719x over previous
//
#include <hip/hip_runtime.h>

// VQ: B=200000 rows (D=128 fp32) vs K=1024 codes; out = [quant B*D | codes B] fp32.
//
// R5: R3 was LDS-pipe-bound (4 ds_read_b128/wave/d, 4 SIMDs share 1 LDS unit);
// R4 moved x to SMEM but waited lgkmcnt(0) right after issue -> serial K$
// latency every 2 dims (VALUBusy 56%). R5 removes BOTH memories from the
// critical path:
//   * codebook pre-transposed to cT[d][k] (512KB ws, L2-resident): lane's 8
//     codes at dim d = contiguous 32B -> coalesced global_load (vmcnt,
//     compiler-managed, issued a pair ahead).
//   * x wave-uniform rows via 8 s_load_dwordx2, software-pipelined one
//     dim-pair ahead; lgkmcnt(0) AFTER the 64-pk compute block (~290cyc
//     covers L2 latency); sched_barrier(0) after the wait (rule #18).
//   * no LDS, no barriers in the main loop; acc lives across all 128 dims
//     -> argmin epilogue once. Block = 16 rows x 1024 codes, 4 waves =
//     2 row-groups x 2 code-halves.
// Numerics: per-(row,code) dot = one serial fma chain over d=0..127, xsq =
// exact 4-chain, dist = fmaf(-2,dot,xsq)+csq, ascending-index tie-breaks ->
// decisions bit-identical to R2/R3/R4 (absmax 0.0).

typedef float v2f __attribute__((ext_vector_type(2)));
typedef int   v2i __attribute__((ext_vector_type(2)));

#define DDIM 128
#define KCODES 1024
#define BMR 16   // rows per block; 200000/16 = 12500 blocks

__global__ void csq_kernel(const float* __restrict__ cb, float* __restrict__ csq) {
    int k = blockIdx.x * blockDim.x + threadIdx.x;
    if (k >= KCODES) return;
    const float* __restrict__ c = cb + (long)k * DDIM;
    float s0 = 0.f, s1 = 0.f, s2 = 0.f, s3 = 0.f;
#pragma unroll
    for (int d = 0; d < DDIM; d += 4) {
        s0 = fmaf(c[d + 0], c[d + 0], s0);
        s1 = fmaf(c[d + 1], c[d + 1], s1);
        s2 = fmaf(c[d + 2], c[d + 2], s2);
        s3 = fmaf(c[d + 3], c[d + 3], s3);
    }
    csq[k] = (s0 + s1) + (s2 + s3);
}

// codebook transpose: cT[d][k] = cb[k][d]  (128 x 1024 fp32, 512 KB)
__global__ void ct_kernel(const float* __restrict__ cb, float* __restrict__ cT) {
    const int idx = blockIdx.x * 256 + threadIdx.x;  // 0..131071
    const int d = idx >> 10, k = idx & 1023;
    cT[idx] = cb[k * DDIM + d];
}

// v_pk_fma_f32, SGPR-pair src0 (x dims d,d+1) broadcast via op_sel.
// PKL: both halves use src0.lo (dim d); PKH: both use src0.hi (dim d+1).
#define PKL(a, xx, cc) \
    asm("v_pk_fma_f32 %0, %1, %2, %0 op_sel:[0,0,0] op_sel_hi:[0,1,1]" \
        : "+v"(a) : "s"(xx), "v"(cc))
#define PKH(a, xx, cc) \
    asm("v_pk_fma_f32 %0, %1, %2, %0 op_sel:[1,0,0] op_sel_hi:[1,1,1]" \
        : "+v"(a) : "s"(xx), "v"(cc))

#define DECLX(S) v2i xq##S##0, xq##S##1, xq##S##2, xq##S##3, \
                     xq##S##4, xq##S##5, xq##S##6, xq##S##7;

// issue 8 s_load_dwordx2 (rows of the wave's group, 2 dims each); NO wait here.
#define ISSUE_X(S, xbp) do { const float* _xb = (xbp); \
    asm volatile( \
        "s_load_dwordx2 %[a0], %[xb], 0x0\n\t" \
        "s_load_dwordx2 %[a1], %[xb], 0x200\n\t" \
        "s_load_dwordx2 %[a2], %[xb], 0x400\n\t" \
        "s_load_dwordx2 %[a3], %[xb], 0x600\n\t" \
        "s_load_dwordx2 %[a4], %[xb], 0x800\n\t" \
        "s_load_dwordx2 %[a5], %[xb], 0xa00\n\t" \
        "s_load_dwordx2 %[a6], %[xb], 0xc00\n\t" \
        "s_load_dwordx2 %[a7], %[xb], 0xe00" \
        : [a0] "=s"(xq##S##0), [a1] "=s"(xq##S##1), \
          [a2] "=s"(xq##S##2), [a3] "=s"(xq##S##3), \
          [a4] "=s"(xq##S##4), [a5] "=s"(xq##S##5), \
          [a6] "=s"(xq##S##6), [a7] "=s"(xq##S##7) \
        : [xb] "s"(_xb)); } while (0)

// one row's 8 codes, dim lo then (later) dim hi
#define CROW_L(S, R) \
    PKL(acc[R][0], xq##S##R, c##S##0); PKL(acc[R][1], xq##S##R, c##S##1); \
    PKL(acc[R][2], xq##S##R, c##S##2); PKL(acc[R][3], xq##S##R, c##S##3);
#define CROW_H(S, R) \
    PKH(acc[R][0], xq##S##R, c##S##4); PKH(acc[R][1], xq##S##R, c##S##5); \
    PKH(acc[R][2], xq##S##R, c##S##6); PKH(acc[R][3], xq##S##R, c##S##7);

#define COMPUTE(S) do { \
    CROW_L(S, 0) CROW_L(S, 1) CROW_L(S, 2) CROW_L(S, 3) \
    CROW_L(S, 4) CROW_L(S, 5) CROW_L(S, 6) CROW_L(S, 7) \
    CROW_H(S, 0) CROW_H(S, 1) CROW_H(S, 2) CROW_H(S, 3) \
    CROW_H(S, 4) CROW_H(S, 5) CROW_H(S, 6) CROW_H(S, 7) } while (0)

__launch_bounds__(256, 4)  // VGPR cap 128 -> 4 blocks/CU (16 waves/CU)
__global__ void vq_kernel(const float* __restrict__ x, const float* __restrict__ cb,
                          const float* __restrict__ cT, const float* __restrict__ csq,
                          float* __restrict__ quant, float* __restrict__ codes) {
    __shared__ float xsqs[BMR];
    __shared__ float redv[4][8];
    __shared__ int   redi[4][8];
    __shared__ int   win[BMR];

    const int tid = threadIdx.x;
    const int lane = tid & 63;
    const int wv = __builtin_amdgcn_readfirstlane(tid >> 6);  // 0..3
    const int rg = wv >> 1;        // row-group: rows rg*8..+7
    const int ch = wv & 1;         // code-half: codes ch*512 + lane*8..+7
    const long r0 = (long)blockIdx.x * BMR;

    // ---- xsq for the block's 16 rows (exact 4-chain, same as R2/R4) ----
    if (tid < BMR) {
        const float* __restrict__ xr = x + (r0 + tid) * DDIM;
        float s0 = 0.f, s1 = 0.f, s2 = 0.f, s3 = 0.f;
#pragma unroll
        for (int q = 0; q < 32; ++q) {
            const float4 v = *(const float4*)(xr + q * 4);
            s0 = fmaf(v.x, v.x, s0);
            s1 = fmaf(v.y, v.y, s1);
            s2 = fmaf(v.z, v.z, s2);
            s3 = fmaf(v.w, v.w, s3);
        }
        xsqs[tid] = (s0 + s1) + (s2 + s3);
    }
    __syncthreads();

    const float* __restrict__ xg = x + (r0 + rg * 8) * DDIM;       // wave-uniform
    const int cbase = ch * 512 + lane * 8;                          // lane's 8 codes
    const float* __restrict__ cT0 = cT + cbase;                     // + d*1024 per dim

    v2f acc[8][4];
#pragma unroll
    for (int r = 0; r < 8; ++r)
#pragma unroll
        for (int j = 0; j < 4; ++j) acc[r][j] = (v2f){0.f, 0.f};

    DECLX(A) DECLX(B)
    v2f cA0, cA1, cA2, cA3, cA4, cA5, cA6, cA7;
    v2f cB0, cB1, cB2, cB3, cB4, cB5, cB6, cB7;

    // ---- prologue: pair 0 into set A ----
    ISSUE_X(A, xg);
    cA0 = *(const v2f*)(cT0);        cA1 = *(const v2f*)(cT0 + 2);
    cA2 = *(const v2f*)(cT0 + 4);    cA3 = *(const v2f*)(cT0 + 6);
    cA4 = *(const v2f*)(cT0 + 1024); cA5 = *(const v2f*)(cT0 + 1026);
    cA6 = *(const v2f*)(cT0 + 1028); cA7 = *(const v2f*)(cT0 + 1030);
    asm volatile("s_waitcnt lgkmcnt(0)" ::: "memory");
    __builtin_amdgcn_sched_barrier(0);

#define STEP(CUR, NXT, pp) do { \
    const int np = ((pp) < 63) ? ((pp) + 1) : 63; \
    ISSUE_X(NXT, xg + np * 2); \
    const float* _ct = cT0 + (long)np * 2048; \
    c##NXT##0 = *(const v2f*)(_ct);        c##NXT##1 = *(const v2f*)(_ct + 2); \
    c##NXT##2 = *(const v2f*)(_ct + 4);    c##NXT##3 = *(const v2f*)(_ct + 6); \
    c##NXT##4 = *(const v2f*)(_ct + 1024); c##NXT##5 = *(const v2f*)(_ct + 1026); \
    c##NXT##6 = *(const v2f*)(_ct + 1028); c##NXT##7 = *(const v2f*)(_ct + 1030); \
    COMPUTE(CUR); \
    asm volatile("s_waitcnt lgkmcnt(0)" ::: "memory"); \
    __builtin_amdgcn_sched_barrier(0); \
} while (0)

#pragma unroll 1
    for (int p = 0; p < 64; p += 2) {
        STEP(A, B, p);
        STEP(B, A, p + 1);
    }
#undef STEP

    // ---- epilogue: dists + in-lane argmin (ascending) + 64-lane butterfly ----
    const float4 cqa = *(const float4*)(csq + cbase);
    const float4 cqb = *(const float4*)(csq + cbase + 4);
    const float cqv[8] = {cqa.x, cqa.y, cqa.z, cqa.w, cqb.x, cqb.y, cqb.z, cqb.w};
#pragma unroll
    for (int r = 0; r < 8; ++r) {
        const float xr = xsqs[rg * 8 + r];
        float b = 3.4e38f; int bi = 0;
#pragma unroll
        for (int j = 0; j < 4; ++j) {
#pragma unroll
            for (int h = 0; h < 2; ++h) {
                const float dist = fmaf(-2.0f, acc[r][j][h], xr) + cqv[j * 2 + h];
                const int idx = cbase + j * 2 + h;
                if (dist < b) { b = dist; bi = idx; }
            }
        }
#pragma unroll
        for (int off = 32; off >= 1; off >>= 1) {
            const float ov = __shfl_xor(b, off);
            const int oi = __shfl_xor(bi, off);
            if (ov < b || (ov == b && oi < bi)) { b = ov; bi = oi; }
        }
        if (lane == 0) { redv[wv][r] = b; redi[wv][r] = bi; }
    }
    __syncthreads();

    // combine the 2 code-halves per row (ascending half = ascending index)
    if (tid < BMR) {
        const int g = tid >> 3, rl = tid & 7;
        float b = redv[g * 2][rl]; int bi = redi[g * 2][rl];
        const float v = redv[g * 2 + 1][rl]; const int vi = redi[g * 2 + 1][rl];
        if (v < b || (v == b && vi < bi)) { b = v; bi = vi; }
        codes[r0 + tid] = (float)bi;
        win[tid] = bi;
    }
    __syncthreads();

    // ---- gather winner rows ----
    {
        const int r = tid >> 4;          // 0..15
        const int s = (tid & 15) * 8;    // 8 floats per thread
        const float* __restrict__ crow = cb + (long)win[r] * DDIM + s;
        float* __restrict__ qrow = quant + (r0 + r) * DDIM + s;
        *(float4*)(qrow) = *(const float4*)(crow);
        *(float4*)(qrow + 4) = *(const float4*)(crow + 4);
    }
}

extern "C" void kernel_launch(void* const* d_in, const int* in_sizes, int n_in,
                              void* d_out, int out_size, void* d_ws, size_t ws_size,
                              hipStream_t stream) {
    const float* x  = (const float*)d_in[0];
    const float* cb = (const float*)d_in[1];
    const int B = in_sizes[0] / DDIM;  // 200000

    float* quant = (float*)d_out;
    float* codes = (float*)d_out + (size_t)B * DDIM;
    float* csq   = (float*)d_ws;                 // 1024 f
    float* cT    = (float*)d_ws + KCODES;        // 128*1024 f = 512 KB

    csq_kernel<<<(KCODES + 255) / 256, 256, 0, stream>>>(cb, csq);
    ct_kernel<<<(DDIM * KCODES) / 256, 256, 0, stream>>>(cb, cT);

    const int blocks = B / BMR;  // 12500 exact
    vq_kernel<<<blocks, 256, 0, stream>>>(x, cb, cT, csq, quant, codes);
}